// Round 2
// baseline (990.818 us; speedup 1.0000x reference)
//
#include <hip/hip_runtime.h>
#include <hip/hip_bf16.h>
#include <stdint.h>

// Fused: Dense(512->256)+BN+LeakyReLU -> LSTM(16x16 -> 128, seq) -> LSTM(128 -> 32) -> Dense(32->10)+softmax
// Strategy: split-bf16 (hi+lo) MFMA everywhere (3x mfma_f32_16x16x32_bf16 per fp32 MAC, ~8e-6 rel err).
// Per-block ownership of 64 batch rows across all 16 timesteps; both LSTMs lockstep per t (hs1 never hits HBM).
// r1 change: bf16 fragment type switched to guide-verified ext_vector_type(8) short (compile-safety).

typedef short bf16x8 __attribute__((ext_vector_type(8)));   // 8 bf16 payloads in 4 VGPRs (guide §3)
typedef float f32x4 __attribute__((ext_vector_type(4)));
typedef unsigned short ushort_t;

#define NTHR 512

__device__ __forceinline__ ushort_t f2bf(float f) {   // fp32 -> bf16 RNE (bit trick)
    unsigned u = __float_as_uint(f);
    u = u + 0x7fffu + ((u >> 16) & 1u);
    return (ushort_t)(u >> 16);
}
__device__ __forceinline__ float bf2f(ushort_t h) {
    return __uint_as_float(((unsigned)h) << 16);
}
__device__ __forceinline__ ushort_t planev(float v, int plane) {
    ushort_t hi = f2bf(v);
    if (plane == 0) return hi;
    return f2bf(v - bf2f(hi));                        // lo residual
}
// fragment-linear weight layout: off = (((nt*KC + kc)*2 + plane)*64 + lane)*8 + j
__device__ __forceinline__ int foff(int nt, int KC, int kc, int plane, int lane) {
    return (((nt * KC + kc) * 2 + plane) * 64 + lane) * 8;
}
__device__ __forceinline__ f32x4 mfma16(bf16x8 a, bf16x8 b, f32x4 c) {
    return __builtin_amdgcn_mfma_f32_16x16x32_bf16(a, b, c, 0, 0, 0);
}
__device__ __forceinline__ float sigm(float x) { return 1.0f / (1.0f + __expf(-x)); }
__device__ __forceinline__ float tanhc(float x) {
    x = fminf(15.0f, fmaxf(-15.0f, x));
    float e = __expf(2.0f * x);
    return (e - 1.0f) / (e + 1.0f);
}

// ---------------- prep: weights -> split-bf16 MFMA fragment layout in ws ----------------
// B-frag semantics: lane l holds W[k][n], n = nt*16 + (l&15), k = kc*32 + (l>>4)*8 + j (j=0..7)
__global__ void prep_weights(const float* __restrict__ Wd1, const float* __restrict__ Wx1,
                             const float* __restrict__ Wh1, const float* __restrict__ Wx2,
                             const float* __restrict__ Wh2, const float* __restrict__ Wd2,
                             ushort_t* __restrict__ wd1f, ushort_t* __restrict__ wh1f,
                             ushort_t* __restrict__ wx1f, ushort_t* __restrict__ w2f,
                             ushort_t* __restrict__ wd2f) {
    const int i = blockIdx.x * blockDim.x + threadIdx.x;   // 0..262143
    const int j = i & 7;
    const int lane = (i >> 3) & 63;
    const int plane = (i >> 9) & 1;
    const int rest = i >> 10;
    const int krow = ((lane >> 4) << 3) + j;
    const int ncol = lane & 15;
    {   // Wd1: K=512 (KC=16), N=256 (NT=16), 262144 slots
        const int kc = rest & 15, nt = rest >> 4;
        const int k = kc * 32 + krow, n = nt * 16 + ncol;
        wd1f[i] = planev(Wd1[k * 256 + n], plane);
    }
    if (i < 131072) {   // Wh1: K=128 (KC=4), N=512 (NT=32)
        const int kc = rest & 3, nt = rest >> 2;
        const int k = kc * 32 + krow, n = nt * 16 + ncol;
        wh1f[i] = planev(Wh1[k * 512 + n], plane);
    }
    if (i < 32768) {    // Wx1: K=16 padded to 32 (KC=1), N=512 (NT=32)
        const int nt = rest;
        const int k = krow, n = nt * 16 + ncol;
        const float v = (k < 16) ? Wx1[k * 512 + n] : 0.f;
        wx1f[i] = planev(v, plane);
    }
    if (i < 40960) {    // W2 = [Wh2(32); Wx2(128)]: K=160 (KC=5), N=128 (NT=8)
        const int kc = rest % 5, nt = rest / 5;
        const int k = kc * 32 + krow, n = nt * 16 + ncol;
        const float v = (k < 32) ? Wh2[k * 128 + n] : Wx2[(k - 32) * 128 + n];
        w2f[i] = planev(v, plane);
    }
    if (i < 1024) {     // Wd2: K=32 (KC=1), N=10 padded to 16 (NT=1)
        const int k = krow, n = ncol;
        const float v = (n < 10) ? Wd2[k * 10 + n] : 0.f;
        wd2f[i] = planev(v, plane);
    }
}

// ---------------- kernel 1: Dense1 + BN + LeakyReLU -> s-fragments (A-operand layout) ----------------
// sfrag element for (row, col): t=col>>4, f=col&15, lane' = (row&15) + 16*(f>>3), j'=f&7, rtg=row>>4
// off = (((rtg*16 + t)*2 + plane)*32 + lane')*8 + j'
__global__ __launch_bounds__(NTHR, 2) void dense1_kernel(
    const float* __restrict__ X, const float* __restrict__ bd1,
    const float* __restrict__ gam, const float* __restrict__ bet,
    const float* __restrict__ mu, const float* __restrict__ var,
    const ushort_t* __restrict__ wd1f, ushort_t* __restrict__ sfrag) {
    __shared__ __align__(16) ushort_t Xs[2][64][40];   // hi/lo planes, 80B row stride (odd x16B)
    const int tid = threadIdx.x;
    const int lane = tid & 63, w = tid >> 6;
    const int l4 = lane >> 4, l15 = lane & 15;
    const int blk = blockIdx.x;
    const long rowbase = (long)blk * 64;

    float bias[2];
#pragma unroll
    for (int ct = 0; ct < 2; ++ct) bias[ct] = bd1[w * 32 + ct * 16 + l15];
    f32x4 acc[4][2];
#pragma unroll
    for (int rt = 0; rt < 4; ++rt)
#pragma unroll
        for (int ct = 0; ct < 2; ++ct) { f32x4 a = {bias[ct], bias[ct], bias[ct], bias[ct]}; acc[rt][ct] = a; }

    const int srow = tid >> 3;   // 0..63
    const int sc4 = tid & 7;     // float4 index within 32-col chunk

#pragma unroll 1
    for (int kc = 0; kc < 16; ++kc) {
        if (kc) __syncthreads();
        const float4 xv = *reinterpret_cast<const float4*>(X + (rowbase + srow) * 512 + kc * 32 + sc4 * 4);
        float x4[4] = {xv.x, xv.y, xv.z, xv.w};
        ushort_t hs[4], ls[4];
#pragma unroll
        for (int q = 0; q < 4; ++q) { hs[q] = f2bf(x4[q]); ls[q] = f2bf(x4[q] - bf2f(hs[q])); }
        *reinterpret_cast<ushort4*>(&Xs[0][srow][sc4 * 4]) = make_ushort4(hs[0], hs[1], hs[2], hs[3]);
        *reinterpret_cast<ushort4*>(&Xs[1][srow][sc4 * 4]) = make_ushort4(ls[0], ls[1], ls[2], ls[3]);
        __syncthreads();

        bf16x8 Ah[4], Al[4];
#pragma unroll
        for (int rt = 0; rt < 4; ++rt) {
            Ah[rt] = *reinterpret_cast<const bf16x8*>(&Xs[0][rt * 16 + l15][l4 * 8]);
            Al[rt] = *reinterpret_cast<const bf16x8*>(&Xs[1][rt * 16 + l15][l4 * 8]);
        }
#pragma unroll
        for (int ct = 0; ct < 2; ++ct) {
            const int nt = w * 2 + ct;
            bf16x8 Bh = *reinterpret_cast<const bf16x8*>(wd1f + foff(nt, 16, kc, 0, lane));
            bf16x8 Bl = *reinterpret_cast<const bf16x8*>(wd1f + foff(nt, 16, kc, 1, lane));
#pragma unroll
            for (int rt = 0; rt < 4; ++rt) {
                acc[rt][ct] = mfma16(Ah[rt], Bh, acc[rt][ct]);
                acc[rt][ct] = mfma16(Ah[rt], Bl, acc[rt][ct]);
                acc[rt][ct] = mfma16(Al[rt], Bh, acc[rt][ct]);
            }
        }
    }

    // epilogue: BN + LeakyReLU + split-bf16 store into s-fragment layout
#pragma unroll
    for (int ct = 0; ct < 2; ++ct) {
        const int col = w * 32 + ct * 16 + l15;
        const float sc = gam[col] * rsqrtf(var[col] + 1e-3f);
        const float sh = bet[col] - mu[col] * sc;
        const int t = col >> 4, f = col & 15;
        const int jp = f & 7;
#pragma unroll
        for (int rt = 0; rt < 4; ++rt) {
            const long rtg = (long)blk * 4 + rt;
#pragma unroll
            for (int jd = 0; jd < 4; ++jd) {
                float v = acc[rt][ct][jd] * sc + sh;
                v = (v >= 0.f) ? v : 0.2f * v;
                const int rowin = l4 * 4 + jd;                 // row within 16-tile (C/D layout, m89)
                const int lanep = rowin + ((f >> 3) << 4);
                const long base = (((rtg * 16 + t) * 2 + 0) * 32 + lanep) * 8 + jp;
                const ushort_t hi = f2bf(v);
                sfrag[base] = hi;
                sfrag[base + 256] = f2bf(v - bf2f(hi));        // plane-1 offset = 32*8
            }
        }
    }
}

// ---------------- kernel 2: LSTM1 + LSTM2 (lockstep) + Dense2 + softmax ----------------
// LDS state A[plane][row 0..63][cols: 0..31 = h2, 32..159 = h1], stride 168 elems (336B, odd x16B)
__global__ __launch_bounds__(NTHR, 2) void lstm_kernel(
    const ushort_t* __restrict__ wh1f, const ushort_t* __restrict__ wx1f,
    const ushort_t* __restrict__ w2f, const ushort_t* __restrict__ wd2f,
    const ushort_t* __restrict__ sfrag, const float* __restrict__ b1,
    const float* __restrict__ b2, const float* __restrict__ bd2,
    float* __restrict__ out) {
    __shared__ __align__(16) ushort_t A[2][64][168];   // 43008 B
    const int tid = threadIdx.x;
    const int lane = tid & 63, w = tid >> 6;
    const int l4 = lane >> 4, l15 = lane & 15;
    const int blk = blockIdx.x;

    {   // zero-init state (h1 = h2 = 0)
        unsigned long long* p = (unsigned long long*)&A[0][0][0];
#pragma unroll 4
        for (int i = tid; i < 2 * 64 * 168 / 4; i += NTHR) p[i] = 0ull;
    }

    float c1[16], hn1[16];
#pragma unroll
    for (int q = 0; q < 16; ++q) c1[q] = 0.f;
    float c2[4];
#pragma unroll
    for (int q = 0; q < 4; ++q) c2[q] = 0.f;

    const int u1 = w * 16 + l15;          // LSTM1: wave w owns units [16w,16w+16)
    float b1g[4];
#pragma unroll
    for (int g = 0; g < 4; ++g) b1g[g] = b1[g * 128 + u1];
    const int rt2 = w & 3;                // LSTM2: wave -> (row-tile, unit-half)
    const int u2base = (w >> 2) * 16;
    float b2g[4];
#pragma unroll
    for (int g = 0; g < 4; ++g) b2g[g] = b2[g * 32 + u2base + l15];

    __syncthreads();

#pragma unroll 1
    for (int t = 0; t < 16; ++t) {
        // ---- LSTM1 z = [h1 | s_t] @ [Wh1; Wx1] + b1 ----
        f32x4 acc1[4][4];
#pragma unroll
        for (int rt = 0; rt < 4; ++rt)
#pragma unroll
            for (int g = 0; g < 4; ++g) { f32x4 a = {b1g[g], b1g[g], b1g[g], b1g[g]}; acc1[rt][g] = a; }

#pragma unroll
        for (int kc = 0; kc < 4; ++kc) {           // h1 part (A cols 32..159)
            bf16x8 Ah[4], Al[4];
#pragma unroll
            for (int rt = 0; rt < 4; ++rt) {
                Ah[rt] = *reinterpret_cast<const bf16x8*>(&A[0][rt * 16 + l15][32 + kc * 32 + l4 * 8]);
                Al[rt] = *reinterpret_cast<const bf16x8*>(&A[1][rt * 16 + l15][32 + kc * 32 + l4 * 8]);
            }
#pragma unroll
            for (int g = 0; g < 4; ++g) {
                const int nt = g * 8 + w;
                bf16x8 Bh = *reinterpret_cast<const bf16x8*>(wh1f + foff(nt, 4, kc, 0, lane));
                bf16x8 Bl = *reinterpret_cast<const bf16x8*>(wh1f + foff(nt, 4, kc, 1, lane));
#pragma unroll
                for (int rt = 0; rt < 4; ++rt) {
                    acc1[rt][g] = mfma16(Ah[rt], Bh, acc1[rt][g]);
                    acc1[rt][g] = mfma16(Ah[rt], Bl, acc1[rt][g]);
                    acc1[rt][g] = mfma16(Al[rt], Bh, acc1[rt][g]);
                }
            }
        }
        {   // s_t part (K=16 padded to 32; weight rows >=16 are zero)
            bf16x8 Sh[4], Sl[4];
#pragma unroll
            for (int rt = 0; rt < 4; ++rt) {
                bf16x8 z = {};
                Sh[rt] = z; Sl[rt] = z;
                if (lane < 32) {
                    const long rtg = (long)blk * 4 + rt;
                    const long so = (((rtg * 16 + t) * 2 + 0) * 32 + lane) * 8;
                    Sh[rt] = *reinterpret_cast<const bf16x8*>(sfrag + so);
                    Sl[rt] = *reinterpret_cast<const bf16x8*>(sfrag + so + 256);
                }
            }
#pragma unroll
            for (int g = 0; g < 4; ++g) {
                const int nt = g * 8 + w;
                bf16x8 Bh = *reinterpret_cast<const bf16x8*>(wx1f + foff(nt, 1, 0, 0, lane));
                bf16x8 Bl = *reinterpret_cast<const bf16x8*>(wx1f + foff(nt, 1, 0, 1, lane));
#pragma unroll
                for (int rt = 0; rt < 4; ++rt) {
                    acc1[rt][g] = mfma16(Sh[rt], Bh, acc1[rt][g]);
                    acc1[rt][g] = mfma16(Sh[rt], Bl, acc1[rt][g]);
                    acc1[rt][g] = mfma16(Sl[rt], Bh, acc1[rt][g]);
                }
            }
        }
        // gates (Keras order i,f,g,o); lane owns unit u1 x 16 rows
#pragma unroll
        for (int rt = 0; rt < 4; ++rt) {
#pragma unroll
            for (int jd = 0; jd < 4; ++jd) {
                const int ci = rt * 4 + jd;
                const float ig = sigm(acc1[rt][0][jd]);
                const float fg = sigm(acc1[rt][1][jd]);
                const float gg = tanhc(acc1[rt][2][jd]);
                const float og = sigm(acc1[rt][3][jd]);
                const float c = fg * c1[ci] + ig * gg;
                c1[ci] = c;
                hn1[ci] = og * tanhc(c);
            }
        }
        __syncthreads();   // B1: all z1 reads of h1_old complete
#pragma unroll
        for (int rt = 0; rt < 4; ++rt) {
#pragma unroll
            for (int jd = 0; jd < 4; ++jd) {
                const int row = rt * 16 + l4 * 4 + jd;
                const float v = hn1[rt * 4 + jd];
                const ushort_t hi = f2bf(v);
                A[0][row][32 + u1] = hi;
                A[1][row][32 + u1] = f2bf(v - bf2f(hi));
            }
        }
        __syncthreads();   // B2: h1_new visible
        // ---- LSTM2 z = [h2_old | h1_new] @ [Wh2; Wx2] + b2 ----
        f32x4 acc2[4];
#pragma unroll
        for (int g = 0; g < 4; ++g) { f32x4 a = {b2g[g], b2g[g], b2g[g], b2g[g]}; acc2[g] = a; }
#pragma unroll
        for (int kc = 0; kc < 5; ++kc) {
            bf16x8 Ah2 = *reinterpret_cast<const bf16x8*>(&A[0][rt2 * 16 + l15][kc * 32 + l4 * 8]);
            bf16x8 Al2 = *reinterpret_cast<const bf16x8*>(&A[1][rt2 * 16 + l15][kc * 32 + l4 * 8]);
#pragma unroll
            for (int g = 0; g < 4; ++g) {
                const int nt = g * 2 + (w >> 2);
                bf16x8 Bh = *reinterpret_cast<const bf16x8*>(w2f + foff(nt, 5, kc, 0, lane));
                bf16x8 Bl = *reinterpret_cast<const bf16x8*>(w2f + foff(nt, 5, kc, 1, lane));
                acc2[g] = mfma16(Ah2, Bh, acc2[g]);
                acc2[g] = mfma16(Ah2, Bl, acc2[g]);
                acc2[g] = mfma16(Al2, Bh, acc2[g]);
            }
        }
        float hn2[4];
#pragma unroll
        for (int jd = 0; jd < 4; ++jd) {
            const float ig = sigm(acc2[0][jd]);
            const float fg = sigm(acc2[1][jd]);
            const float gg = tanhc(acc2[2][jd]);
            const float og = sigm(acc2[3][jd]);
            const float c = fg * c2[jd] + ig * gg;
            c2[jd] = c;
            hn2[jd] = og * tanhc(c);
        }
        __syncthreads();   // B3: all z2 reads of h2_old complete
#pragma unroll
        for (int jd = 0; jd < 4; ++jd) {
            const int row = rt2 * 16 + l4 * 4 + jd;
            const float v = hn2[jd];
            const ushort_t hi = f2bf(v);
            A[0][row][u2base + l15] = hi;
            A[1][row][u2base + l15] = f2bf(v - bf2f(hi));
        }
        // next z1 reads only h1 cols (no race with h2 writes); next z2 is behind B1+B2
    }
    __syncthreads();       // final h2 visible

    // ---- Dense2 (K=32) + softmax over 10 classes ----
    if (w < 4) {
        const int rt = w;
        bf16x8 Ah2 = *reinterpret_cast<const bf16x8*>(&A[0][rt * 16 + l15][l4 * 8]);
        bf16x8 Al2 = *reinterpret_cast<const bf16x8*>(&A[1][rt * 16 + l15][l4 * 8]);
        bf16x8 Bh = *reinterpret_cast<const bf16x8*>(wd2f + foff(0, 1, 0, 0, lane));
        bf16x8 Bl = *reinterpret_cast<const bf16x8*>(wd2f + foff(0, 1, 0, 1, lane));
        const float bb = (l15 < 10) ? bd2[l15] : 0.f;
        f32x4 accd = {bb, bb, bb, bb};
        accd = mfma16(Ah2, Bh, accd);
        accd = mfma16(Ah2, Bl, accd);
        accd = mfma16(Al2, Bh, accd);
#pragma unroll
        for (int jd = 0; jd < 4; ++jd) {
            float v = (l15 < 10) ? accd[jd] : -1e30f;
            float m = v;
            m = fmaxf(m, __shfl_xor(m, 1));
            m = fmaxf(m, __shfl_xor(m, 2));
            m = fmaxf(m, __shfl_xor(m, 4));
            m = fmaxf(m, __shfl_xor(m, 8));
            float e = (l15 < 10) ? __expf(v - m) : 0.f;
            float s = e;
            s += __shfl_xor(s, 1);
            s += __shfl_xor(s, 2);
            s += __shfl_xor(s, 4);
            s += __shfl_xor(s, 8);
            if (l15 < 10) {
                const long r = (long)blk * 64 + rt * 16 + l4 * 4 + jd;
                out[r * 10 + l15] = e / s;
            }
        }
    }
}

extern "C" void kernel_launch(void* const* d_in, const int* in_sizes, int n_in,
                              void* d_out, int out_size, void* d_ws, size_t ws_size,
                              hipStream_t stream) {
    const float* x   = (const float*)d_in[0];
    const float* Wd1 = (const float*)d_in[1];
    const float* bd1 = (const float*)d_in[2];
    const float* gam = (const float*)d_in[3];
    const float* bet = (const float*)d_in[4];
    const float* mu  = (const float*)d_in[5];
    const float* var = (const float*)d_in[6];
    const float* Wx1 = (const float*)d_in[7];
    const float* Wh1 = (const float*)d_in[8];
    const float* b1  = (const float*)d_in[9];
    const float* Wx2 = (const float*)d_in[10];
    const float* Wh2 = (const float*)d_in[11];
    const float* b2  = (const float*)d_in[12];
    const float* Wd2 = (const float*)d_in[13];
    const float* bd2 = (const float*)d_in[14];
    float* out = (float*)d_out;

    char* ws = (char*)d_ws;
    ushort_t* wd1f  = (ushort_t*)(ws);             // 524288 B
    ushort_t* wh1f  = (ushort_t*)(ws + 524288);    // 262144 B
    ushort_t* wx1f  = (ushort_t*)(ws + 786432);    // 65536 B
    ushort_t* w2f   = (ushort_t*)(ws + 851968);    // 81920 B
    ushort_t* wd2f  = (ushort_t*)(ws + 933888);    // 2048 B
    ushort_t* sfrag = (ushort_t*)(ws + 935936);    // 33554432 B  (total ~34.5 MB)

    hipLaunchKernelGGL(prep_weights, dim3(512), dim3(512), 0, stream,
                       Wd1, Wx1, Wh1, Wx2, Wh2, Wd2, wd1f, wh1f, wx1f, w2f, wd2f);
    hipLaunchKernelGGL(dense1_kernel, dim3(512), dim3(512), 0, stream,
                       x, bd1, gam, bet, mu, var, wd1f, sfrag);
    hipLaunchKernelGGL(lstm_kernel, dim3(512), dim3(512), 0, stream,
                       wh1f, wx1f, w2f, wd2f, sfrag, b1, b2, bd2, out);
}

// Round 6
// 988.482 us; speedup vs baseline: 1.0024x; 1.0024x over previous
//
#include <hip/hip_runtime.h>
#include <hip/hip_bf16.h>
#include <stdint.h>

// Fused: Dense(512->256)+BN+LeakyReLU -> LSTM(16x16 -> 128, seq) -> LSTM(128 -> 32) -> Dense(32->10)+softmax
// Strategy: split-bf16 (hi+lo) MFMA everywhere (3x mfma_f32_16x16x32_bf16 per fp32 MAC, ~8e-6 rel err).
// Per-block ownership of 64 batch rows across all 16 timesteps; both LSTMs lockstep per t (hs1 never hits HBM).
// r2 diagnosis: WRITE_SIZE=267MB (output is 1.3MB) => register spills, 2.3GB scratch round-trip = the 910us.
// r3 change (resubmitted r4-r6; benches never acquired a GPU): lstm_kernel __launch_bounds__(512,2) -> (512,1).
//            Live set ~142-160 VGPR; the 128-cap forced ~16 spilled regs/lane re-spilled every timestep.
//            512-thread block => 2 waves/SIMD resident => allocator may use up to 256 VGPR: no spills.

typedef short bf16x8 __attribute__((ext_vector_type(8)));   // 8 bf16 payloads in 4 VGPRs (guide §3)
typedef float f32x4 __attribute__((ext_vector_type(4)));
typedef unsigned short ushort_t;

#define NTHR 512

__device__ __forceinline__ ushort_t f2bf(float f) {   // fp32 -> bf16 RNE (bit trick)
    unsigned u = __float_as_uint(f);
    u = u + 0x7fffu + ((u >> 16) & 1u);
    return (ushort_t)(u >> 16);
}
__device__ __forceinline__ float bf2f(ushort_t h) {
    return __uint_as_float(((unsigned)h) << 16);
}
__device__ __forceinline__ ushort_t planev(float v, int plane) {
    ushort_t hi = f2bf(v);
    if (plane == 0) return hi;
    return f2bf(v - bf2f(hi));                        // lo residual
}
// fragment-linear weight layout: off = (((nt*KC + kc)*2 + plane)*64 + lane)*8 + j
__device__ __forceinline__ int foff(int nt, int KC, int kc, int plane, int lane) {
    return (((nt * KC + kc) * 2 + plane) * 64 + lane) * 8;
}
__device__ __forceinline__ f32x4 mfma16(bf16x8 a, bf16x8 b, f32x4 c) {
    return __builtin_amdgcn_mfma_f32_16x16x32_bf16(a, b, c, 0, 0, 0);
}
__device__ __forceinline__ float sigm(float x) { return 1.0f / (1.0f + __expf(-x)); }
__device__ __forceinline__ float tanhc(float x) {
    x = fminf(15.0f, fmaxf(-15.0f, x));
    float e = __expf(2.0f * x);
    return (e - 1.0f) / (e + 1.0f);
}

// ---------------- prep: weights -> split-bf16 MFMA fragment layout in ws ----------------
// B-frag semantics: lane l holds W[k][n], n = nt*16 + (l&15), k = kc*32 + (l>>4)*8 + j (j=0..7)
__global__ void prep_weights(const float* __restrict__ Wd1, const float* __restrict__ Wx1,
                             const float* __restrict__ Wh1, const float* __restrict__ Wx2,
                             const float* __restrict__ Wh2, const float* __restrict__ Wd2,
                             ushort_t* __restrict__ wd1f, ushort_t* __restrict__ wh1f,
                             ushort_t* __restrict__ wx1f, ushort_t* __restrict__ w2f,
                             ushort_t* __restrict__ wd2f) {
    const int i = blockIdx.x * blockDim.x + threadIdx.x;   // 0..262143
    const int j = i & 7;
    const int lane = (i >> 3) & 63;
    const int plane = (i >> 9) & 1;
    const int rest = i >> 10;
    const int krow = ((lane >> 4) << 3) + j;
    const int ncol = lane & 15;
    {   // Wd1: K=512 (KC=16), N=256 (NT=16), 262144 slots
        const int kc = rest & 15, nt = rest >> 4;
        const int k = kc * 32 + krow, n = nt * 16 + ncol;
        wd1f[i] = planev(Wd1[k * 256 + n], plane);
    }
    if (i < 131072) {   // Wh1: K=128 (KC=4), N=512 (NT=32)
        const int kc = rest & 3, nt = rest >> 2;
        const int k = kc * 32 + krow, n = nt * 16 + ncol;
        wh1f[i] = planev(Wh1[k * 512 + n], plane);
    }
    if (i < 32768) {    // Wx1: K=16 padded to 32 (KC=1), N=512 (NT=32)
        const int nt = rest;
        const int k = krow, n = nt * 16 + ncol;
        const float v = (k < 16) ? Wx1[k * 512 + n] : 0.f;
        wx1f[i] = planev(v, plane);
    }
    if (i < 40960) {    // W2 = [Wh2(32); Wx2(128)]: K=160 (KC=5), N=128 (NT=8)
        const int kc = rest % 5, nt = rest / 5;
        const int k = kc * 32 + krow, n = nt * 16 + ncol;
        const float v = (k < 32) ? Wh2[k * 128 + n] : Wx2[(k - 32) * 128 + n];
        w2f[i] = planev(v, plane);
    }
    if (i < 1024) {     // Wd2: K=32 (KC=1), N=10 padded to 16 (NT=1)
        const int k = krow, n = ncol;
        const float v = (n < 10) ? Wd2[k * 10 + n] : 0.f;
        wd2f[i] = planev(v, plane);
    }
}

// ---------------- kernel 1: Dense1 + BN + LeakyReLU -> s-fragments (A-operand layout) ----------------
// sfrag element for (row, col): t=col>>4, f=col&15, lane' = (row&15) + 16*(f>>3), j'=f&7, rtg=row>>4
// off = (((rtg*16 + t)*2 + plane)*32 + lane')*8 + j'
__global__ __launch_bounds__(NTHR, 2) void dense1_kernel(
    const float* __restrict__ X, const float* __restrict__ bd1,
    const float* __restrict__ gam, const float* __restrict__ bet,
    const float* __restrict__ mu, const float* __restrict__ var,
    const ushort_t* __restrict__ wd1f, ushort_t* __restrict__ sfrag) {
    __shared__ __align__(16) ushort_t Xs[2][64][40];   // hi/lo planes, 80B row stride (odd x16B)
    const int tid = threadIdx.x;
    const int lane = tid & 63, w = tid >> 6;
    const int l4 = lane >> 4, l15 = lane & 15;
    const int blk = blockIdx.x;
    const long rowbase = (long)blk * 64;

    float bias[2];
#pragma unroll
    for (int ct = 0; ct < 2; ++ct) bias[ct] = bd1[w * 32 + ct * 16 + l15];
    f32x4 acc[4][2];
#pragma unroll
    for (int rt = 0; rt < 4; ++rt)
#pragma unroll
        for (int ct = 0; ct < 2; ++ct) { f32x4 a = {bias[ct], bias[ct], bias[ct], bias[ct]}; acc[rt][ct] = a; }

    const int srow = tid >> 3;   // 0..63
    const int sc4 = tid & 7;     // float4 index within 32-col chunk

#pragma unroll 1
    for (int kc = 0; kc < 16; ++kc) {
        if (kc) __syncthreads();
        const float4 xv = *reinterpret_cast<const float4*>(X + (rowbase + srow) * 512 + kc * 32 + sc4 * 4);
        float x4[4] = {xv.x, xv.y, xv.z, xv.w};
        ushort_t hs[4], ls[4];
#pragma unroll
        for (int q = 0; q < 4; ++q) { hs[q] = f2bf(x4[q]); ls[q] = f2bf(x4[q] - bf2f(hs[q])); }
        *reinterpret_cast<ushort4*>(&Xs[0][srow][sc4 * 4]) = make_ushort4(hs[0], hs[1], hs[2], hs[3]);
        *reinterpret_cast<ushort4*>(&Xs[1][srow][sc4 * 4]) = make_ushort4(ls[0], ls[1], ls[2], ls[3]);
        __syncthreads();

        bf16x8 Ah[4], Al[4];
#pragma unroll
        for (int rt = 0; rt < 4; ++rt) {
            Ah[rt] = *reinterpret_cast<const bf16x8*>(&Xs[0][rt * 16 + l15][l4 * 8]);
            Al[rt] = *reinterpret_cast<const bf16x8*>(&Xs[1][rt * 16 + l15][l4 * 8]);
        }
#pragma unroll
        for (int ct = 0; ct < 2; ++ct) {
            const int nt = w * 2 + ct;
            bf16x8 Bh = *reinterpret_cast<const bf16x8*>(wd1f + foff(nt, 16, kc, 0, lane));
            bf16x8 Bl = *reinterpret_cast<const bf16x8*>(wd1f + foff(nt, 16, kc, 1, lane));
#pragma unroll
            for (int rt = 0; rt < 4; ++rt) {
                acc[rt][ct] = mfma16(Ah[rt], Bh, acc[rt][ct]);
                acc[rt][ct] = mfma16(Ah[rt], Bl, acc[rt][ct]);
                acc[rt][ct] = mfma16(Al[rt], Bh, acc[rt][ct]);
            }
        }
    }

    // epilogue: BN + LeakyReLU + split-bf16 store into s-fragment layout
#pragma unroll
    for (int ct = 0; ct < 2; ++ct) {
        const int col = w * 32 + ct * 16 + l15;
        const float sc = gam[col] * rsqrtf(var[col] + 1e-3f);
        const float sh = bet[col] - mu[col] * sc;
        const int t = col >> 4, f = col & 15;
        const int jp = f & 7;
#pragma unroll
        for (int rt = 0; rt < 4; ++rt) {
            const long rtg = (long)blk * 4 + rt;
#pragma unroll
            for (int jd = 0; jd < 4; ++jd) {
                float v = acc[rt][ct][jd] * sc + sh;
                v = (v >= 0.f) ? v : 0.2f * v;
                const int rowin = l4 * 4 + jd;                 // row within 16-tile (C/D layout, m89)
                const int lanep = rowin + ((f >> 3) << 4);
                const long base = (((rtg * 16 + t) * 2 + 0) * 32 + lanep) * 8 + jp;
                const ushort_t hi = f2bf(v);
                sfrag[base] = hi;
                sfrag[base + 256] = f2bf(v - bf2f(hi));        // plane-1 offset = 32*8
            }
        }
    }
}

// ---------------- kernel 2: LSTM1 + LSTM2 (lockstep) + Dense2 + softmax ----------------
// LDS state A[plane][row 0..63][cols: 0..31 = h2, 32..159 = h1], stride 168 elems (336B, odd x16B)
__global__ __launch_bounds__(NTHR, 1) void lstm_kernel(
    const ushort_t* __restrict__ wh1f, const ushort_t* __restrict__ wx1f,
    const ushort_t* __restrict__ w2f, const ushort_t* __restrict__ wd2f,
    const ushort_t* __restrict__ sfrag, const float* __restrict__ b1,
    const float* __restrict__ b2, const float* __restrict__ bd2,
    float* __restrict__ out) {
    __shared__ __align__(16) ushort_t A[2][64][168];   // 43008 B
    const int tid = threadIdx.x;
    const int lane = tid & 63, w = tid >> 6;
    const int l4 = lane >> 4, l15 = lane & 15;
    const int blk = blockIdx.x;

    {   // zero-init state (h1 = h2 = 0)
        unsigned long long* p = (unsigned long long*)&A[0][0][0];
#pragma unroll 4
        for (int i = tid; i < 2 * 64 * 168 / 4; i += NTHR) p[i] = 0ull;
    }

    float c1[16], hn1[16];
#pragma unroll
    for (int q = 0; q < 16; ++q) c1[q] = 0.f;
    float c2[4];
#pragma unroll
    for (int q = 0; q < 4; ++q) c2[q] = 0.f;

    const int u1 = w * 16 + l15;          // LSTM1: wave w owns units [16w,16w+16)
    float b1g[4];
#pragma unroll
    for (int g = 0; g < 4; ++g) b1g[g] = b1[g * 128 + u1];
    const int rt2 = w & 3;                // LSTM2: wave -> (row-tile, unit-half)
    const int u2base = (w >> 2) * 16;
    float b2g[4];
#pragma unroll
    for (int g = 0; g < 4; ++g) b2g[g] = b2[g * 32 + u2base + l15];

    __syncthreads();

#pragma unroll 1
    for (int t = 0; t < 16; ++t) {
        // ---- LSTM1 z = [h1 | s_t] @ [Wh1; Wx1] + b1 ----
        f32x4 acc1[4][4];
#pragma unroll
        for (int rt = 0; rt < 4; ++rt)
#pragma unroll
            for (int g = 0; g < 4; ++g) { f32x4 a = {b1g[g], b1g[g], b1g[g], b1g[g]}; acc1[rt][g] = a; }

#pragma unroll
        for (int kc = 0; kc < 4; ++kc) {           // h1 part (A cols 32..159)
            bf16x8 Ah[4], Al[4];
#pragma unroll
            for (int rt = 0; rt < 4; ++rt) {
                Ah[rt] = *reinterpret_cast<const bf16x8*>(&A[0][rt * 16 + l15][32 + kc * 32 + l4 * 8]);
                Al[rt] = *reinterpret_cast<const bf16x8*>(&A[1][rt * 16 + l15][32 + kc * 32 + l4 * 8]);
            }
#pragma unroll
            for (int g = 0; g < 4; ++g) {
                const int nt = g * 8 + w;
                bf16x8 Bh = *reinterpret_cast<const bf16x8*>(wh1f + foff(nt, 4, kc, 0, lane));
                bf16x8 Bl = *reinterpret_cast<const bf16x8*>(wh1f + foff(nt, 4, kc, 1, lane));
#pragma unroll
                for (int rt = 0; rt < 4; ++rt) {
                    acc1[rt][g] = mfma16(Ah[rt], Bh, acc1[rt][g]);
                    acc1[rt][g] = mfma16(Ah[rt], Bl, acc1[rt][g]);
                    acc1[rt][g] = mfma16(Al[rt], Bh, acc1[rt][g]);
                }
            }
        }
        {   // s_t part (K=16 padded to 32; weight rows >=16 are zero)
            bf16x8 Sh[4], Sl[4];
#pragma unroll
            for (int rt = 0; rt < 4; ++rt) {
                bf16x8 z = {};
                Sh[rt] = z; Sl[rt] = z;
                if (lane < 32) {
                    const long rtg = (long)blk * 4 + rt;
                    const long so = (((rtg * 16 + t) * 2 + 0) * 32 + lane) * 8;
                    Sh[rt] = *reinterpret_cast<const bf16x8*>(sfrag + so);
                    Sl[rt] = *reinterpret_cast<const bf16x8*>(sfrag + so + 256);
                }
            }
#pragma unroll
            for (int g = 0; g < 4; ++g) {
                const int nt = g * 8 + w;
                bf16x8 Bh = *reinterpret_cast<const bf16x8*>(wx1f + foff(nt, 1, 0, 0, lane));
                bf16x8 Bl = *reinterpret_cast<const bf16x8*>(wx1f + foff(nt, 1, 0, 1, lane));
#pragma unroll
                for (int rt = 0; rt < 4; ++rt) {
                    acc1[rt][g] = mfma16(Sh[rt], Bh, acc1[rt][g]);
                    acc1[rt][g] = mfma16(Sh[rt], Bl, acc1[rt][g]);
                    acc1[rt][g] = mfma16(Sl[rt], Bh, acc1[rt][g]);
                }
            }
        }
        // gates (Keras order i,f,g,o); lane owns unit u1 x 16 rows
#pragma unroll
        for (int rt = 0; rt < 4; ++rt) {
#pragma unroll
            for (int jd = 0; jd < 4; ++jd) {
                const int ci = rt * 4 + jd;
                const float ig = sigm(acc1[rt][0][jd]);
                const float fg = sigm(acc1[rt][1][jd]);
                const float gg = tanhc(acc1[rt][2][jd]);
                const float og = sigm(acc1[rt][3][jd]);
                const float c = fg * c1[ci] + ig * gg;
                c1[ci] = c;
                hn1[ci] = og * tanhc(c);
            }
        }
        __syncthreads();   // B1: all z1 reads of h1_old complete
#pragma unroll
        for (int rt = 0; rt < 4; ++rt) {
#pragma unroll
            for (int jd = 0; jd < 4; ++jd) {
                const int row = rt * 16 + l4 * 4 + jd;
                const float v = hn1[rt * 4 + jd];
                const ushort_t hi = f2bf(v);
                A[0][row][32 + u1] = hi;
                A[1][row][32 + u1] = f2bf(v - bf2f(hi));
            }
        }
        __syncthreads();   // B2: h1_new visible
        // ---- LSTM2 z = [h2_old | h1_new] @ [Wh2; Wx2] + b2 ----
        f32x4 acc2[4];
#pragma unroll
        for (int g = 0; g < 4; ++g) { f32x4 a = {b2g[g], b2g[g], b2g[g], b2g[g]}; acc2[g] = a; }
#pragma unroll
        for (int kc = 0; kc < 5; ++kc) {
            bf16x8 Ah2 = *reinterpret_cast<const bf16x8*>(&A[0][rt2 * 16 + l15][kc * 32 + l4 * 8]);
            bf16x8 Al2 = *reinterpret_cast<const bf16x8*>(&A[1][rt2 * 16 + l15][kc * 32 + l4 * 8]);
#pragma unroll
            for (int g = 0; g < 4; ++g) {
                const int nt = g * 2 + (w >> 2);
                bf16x8 Bh = *reinterpret_cast<const bf16x8*>(w2f + foff(nt, 5, kc, 0, lane));
                bf16x8 Bl = *reinterpret_cast<const bf16x8*>(w2f + foff(nt, 5, kc, 1, lane));
                acc2[g] = mfma16(Ah2, Bh, acc2[g]);
                acc2[g] = mfma16(Ah2, Bl, acc2[g]);
                acc2[g] = mfma16(Al2, Bh, acc2[g]);
            }
        }
        float hn2[4];
#pragma unroll
        for (int jd = 0; jd < 4; ++jd) {
            const float ig = sigm(acc2[0][jd]);
            const float fg = sigm(acc2[1][jd]);
            const float gg = tanhc(acc2[2][jd]);
            const float og = sigm(acc2[3][jd]);
            const float c = fg * c2[jd] + ig * gg;
            c2[jd] = c;
            hn2[jd] = og * tanhc(c);
        }
        __syncthreads();   // B3: all z2 reads of h2_old complete
#pragma unroll
        for (int jd = 0; jd < 4; ++jd) {
            const int row = rt2 * 16 + l4 * 4 + jd;
            const float v = hn2[jd];
            const ushort_t hi = f2bf(v);
            A[0][row][u2base + l15] = hi;
            A[1][row][u2base + l15] = f2bf(v - bf2f(hi));
        }
        // next z1 reads only h1 cols (no race with h2 writes); next z2 is behind B1+B2
    }
    __syncthreads();       // final h2 visible

    // ---- Dense2 (K=32) + softmax over 10 classes ----
    if (w < 4) {
        const int rt = w;
        bf16x8 Ah2 = *reinterpret_cast<const bf16x8*>(&A[0][rt * 16 + l15][l4 * 8]);
        bf16x8 Al2 = *reinterpret_cast<const bf16x8*>(&A[1][rt * 16 + l15][l4 * 8]);
        bf16x8 Bh = *reinterpret_cast<const bf16x8*>(wd2f + foff(0, 1, 0, 0, lane));
        bf16x8 Bl = *reinterpret_cast<const bf16x8*>(wd2f + foff(0, 1, 0, 1, lane));
        const float bb = (l15 < 10) ? bd2[l15] : 0.f;
        f32x4 accd = {bb, bb, bb, bb};
        accd = mfma16(Ah2, Bh, accd);
        accd = mfma16(Ah2, Bl, accd);
        accd = mfma16(Al2, Bh, accd);
#pragma unroll
        for (int jd = 0; jd < 4; ++jd) {
            float v = (l15 < 10) ? accd[jd] : -1e30f;
            float m = v;
            m = fmaxf(m, __shfl_xor(m, 1));
            m = fmaxf(m, __shfl_xor(m, 2));
            m = fmaxf(m, __shfl_xor(m, 4));
            m = fmaxf(m, __shfl_xor(m, 8));
            float e = (l15 < 10) ? __expf(v - m) : 0.f;
            float s = e;
            s += __shfl_xor(s, 1);
            s += __shfl_xor(s, 2);
            s += __shfl_xor(s, 4);
            s += __shfl_xor(s, 8);
            if (l15 < 10) {
                const long r = (long)blk * 64 + rt * 16 + l4 * 4 + jd;
                out[r * 10 + l15] = e / s;
            }
        }
    }
}

extern "C" void kernel_launch(void* const* d_in, const int* in_sizes, int n_in,
                              void* d_out, int out_size, void* d_ws, size_t ws_size,
                              hipStream_t stream) {
    const float* x   = (const float*)d_in[0];
    const float* Wd1 = (const float*)d_in[1];
    const float* bd1 = (const float*)d_in[2];
    const float* gam = (const float*)d_in[3];
    const float* bet = (const float*)d_in[4];
    const float* mu  = (const float*)d_in[5];
    const float* var = (const float*)d_in[6];
    const float* Wx1 = (const float*)d_in[7];
    const float* Wh1 = (const float*)d_in[8];
    const float* b1  = (const float*)d_in[9];
    const float* Wx2 = (const float*)d_in[10];
    const float* Wh2 = (const float*)d_in[11];
    const float* b2  = (const float*)d_in[12];
    const float* Wd2 = (const float*)d_in[13];
    const float* bd2 = (const float*)d_in[14];
    float* out = (float*)d_out;

    char* ws = (char*)d_ws;
    ushort_t* wd1f  = (ushort_t*)(ws);             // 524288 B
    ushort_t* wh1f  = (ushort_t*)(ws + 524288);    // 262144 B
    ushort_t* wx1f  = (ushort_t*)(ws + 786432);    // 65536 B
    ushort_t* w2f   = (ushort_t*)(ws + 851968);    // 81920 B
    ushort_t* wd2f  = (ushort_t*)(ws + 933888);    // 2048 B
    ushort_t* sfrag = (ushort_t*)(ws + 935936);    // 33554432 B  (total ~34.5 MB)

    hipLaunchKernelGGL(prep_weights, dim3(512), dim3(512), 0, stream,
                       Wd1, Wx1, Wh1, Wx2, Wh2, Wd2, wd1f, wh1f, wx1f, w2f, wd2f);
    hipLaunchKernelGGL(dense1_kernel, dim3(512), dim3(512), 0, stream,
                       x, bd1, gam, bet, mu, var, wd1f, sfrag);
    hipLaunchKernelGGL(lstm_kernel, dim3(512), dim3(512), 0, stream,
                       wh1f, wx1f, w2f, wd2f, sfrag, b1, b2, bd2, out);
}

// Round 10
// 971.932 us; speedup vs baseline: 1.0194x; 1.0170x over previous
//
#include <hip/hip_runtime.h>
#include <hip/hip_bf16.h>
#include <stdint.h>

// Fused: Dense(512->256)+BN+LeakyReLU -> LSTM(16x16 -> 128, seq) -> LSTM(128 -> 32) -> Dense(32->10)+softmax
// Strategy: split-bf16 (hi+lo) MFMA everywhere (3x mfma_f32_16x16x32_bf16 per fp32 MAC, ~8e-6 rel err).
// r2/r6 diagnosis: WRITE_SIZE=267MB (output is 1.3MB) => ~16 regs/lane spilled every timestep (live ~140 vs
//   compiler's self-chosen 128 target); spill stream thrashes L2 => 400KB of weight frags re-fetched from HBM
//   every (block,timestep) => FETCH=2.04GB. launch_bounds (512,2)->(512,1) produced an identical binary:
//   the allocator's occupancy target can't be raised by the hint. Fix must be structural.
// r7 change (resubmitted r8-r10; benches never acquired a GPU): shrink lstm peak live set ~140 -> ~115:
//   (a) hn1[16] deleted - gates computed AFTER barrier B1, h1 written to LDS inline (same barrier schedule);
//   (b) c1[16] moved to LDS C1[64][132] fp32 (pad 132: 2-way bank aliasing only = free per m136).
//   LDS 43008+33792=76.8KB -> still 2 blocks/CU; no spills at 128-VGPR target, 4 waves/SIMD kept.

typedef short bf16x8 __attribute__((ext_vector_type(8)));   // 8 bf16 payloads in 4 VGPRs (guide §3)
typedef float f32x4 __attribute__((ext_vector_type(4)));
typedef unsigned short ushort_t;

#define NTHR 512

__device__ __forceinline__ ushort_t f2bf(float f) {   // fp32 -> bf16 RNE (bit trick)
    unsigned u = __float_as_uint(f);
    u = u + 0x7fffu + ((u >> 16) & 1u);
    return (ushort_t)(u >> 16);
}
__device__ __forceinline__ float bf2f(ushort_t h) {
    return __uint_as_float(((unsigned)h) << 16);
}
__device__ __forceinline__ ushort_t planev(float v, int plane) {
    ushort_t hi = f2bf(v);
    if (plane == 0) return hi;
    return f2bf(v - bf2f(hi));                        // lo residual
}
// fragment-linear weight layout: off = (((nt*KC + kc)*2 + plane)*64 + lane)*8 + j
__device__ __forceinline__ int foff(int nt, int KC, int kc, int plane, int lane) {
    return (((nt * KC + kc) * 2 + plane) * 64 + lane) * 8;
}
__device__ __forceinline__ f32x4 mfma16(bf16x8 a, bf16x8 b, f32x4 c) {
    return __builtin_amdgcn_mfma_f32_16x16x32_bf16(a, b, c, 0, 0, 0);
}
__device__ __forceinline__ float sigm(float x) { return 1.0f / (1.0f + __expf(-x)); }
__device__ __forceinline__ float tanhc(float x) {
    x = fminf(15.0f, fmaxf(-15.0f, x));
    float e = __expf(2.0f * x);
    return (e - 1.0f) / (e + 1.0f);
}

// ---------------- prep: weights -> split-bf16 MFMA fragment layout in ws ----------------
// B-frag semantics: lane l holds W[k][n], n = nt*16 + (l&15), k = kc*32 + (l>>4)*8 + j (j=0..7)
__global__ void prep_weights(const float* __restrict__ Wd1, const float* __restrict__ Wx1,
                             const float* __restrict__ Wh1, const float* __restrict__ Wx2,
                             const float* __restrict__ Wh2, const float* __restrict__ Wd2,
                             ushort_t* __restrict__ wd1f, ushort_t* __restrict__ wh1f,
                             ushort_t* __restrict__ wx1f, ushort_t* __restrict__ w2f,
                             ushort_t* __restrict__ wd2f) {
    const int i = blockIdx.x * blockDim.x + threadIdx.x;   // 0..262143
    const int j = i & 7;
    const int lane = (i >> 3) & 63;
    const int plane = (i >> 9) & 1;
    const int rest = i >> 10;
    const int krow = ((lane >> 4) << 3) + j;
    const int ncol = lane & 15;
    {   // Wd1: K=512 (KC=16), N=256 (NT=16), 262144 slots
        const int kc = rest & 15, nt = rest >> 4;
        const int k = kc * 32 + krow, n = nt * 16 + ncol;
        wd1f[i] = planev(Wd1[k * 256 + n], plane);
    }
    if (i < 131072) {   // Wh1: K=128 (KC=4), N=512 (NT=32)
        const int kc = rest & 3, nt = rest >> 2;
        const int k = kc * 32 + krow, n = nt * 16 + ncol;
        wh1f[i] = planev(Wh1[k * 512 + n], plane);
    }
    if (i < 32768) {    // Wx1: K=16 padded to 32 (KC=1), N=512 (NT=32)
        const int nt = rest;
        const int k = krow, n = nt * 16 + ncol;
        const float v = (k < 16) ? Wx1[k * 512 + n] : 0.f;
        wx1f[i] = planev(v, plane);
    }
    if (i < 40960) {    // W2 = [Wh2(32); Wx2(128)]: K=160 (KC=5), N=128 (NT=8)
        const int kc = rest % 5, nt = rest / 5;
        const int k = kc * 32 + krow, n = nt * 16 + ncol;
        const float v = (k < 32) ? Wh2[k * 128 + n] : Wx2[(k - 32) * 128 + n];
        w2f[i] = planev(v, plane);
    }
    if (i < 1024) {     // Wd2: K=32 (KC=1), N=10 padded to 16 (NT=1)
        const int k = krow, n = ncol;
        const float v = (n < 10) ? Wd2[k * 10 + n] : 0.f;
        wd2f[i] = planev(v, plane);
    }
}

// ---------------- kernel 1: Dense1 + BN + LeakyReLU -> s-fragments (A-operand layout) ----------------
// sfrag element for (row, col): t=col>>4, f=col&15, lane' = (row&15) + 16*(f>>3), j'=f&7, rtg=row>>4
// off = (((rtg*16 + t)*2 + plane)*32 + lane')*8 + j'
__global__ __launch_bounds__(NTHR, 2) void dense1_kernel(
    const float* __restrict__ X, const float* __restrict__ bd1,
    const float* __restrict__ gam, const float* __restrict__ bet,
    const float* __restrict__ mu, const float* __restrict__ var,
    const ushort_t* __restrict__ wd1f, ushort_t* __restrict__ sfrag) {
    __shared__ __align__(16) ushort_t Xs[2][64][40];   // hi/lo planes, 80B row stride (odd x16B)
    const int tid = threadIdx.x;
    const int lane = tid & 63, w = tid >> 6;
    const int l4 = lane >> 4, l15 = lane & 15;
    const int blk = blockIdx.x;
    const long rowbase = (long)blk * 64;

    float bias[2];
#pragma unroll
    for (int ct = 0; ct < 2; ++ct) bias[ct] = bd1[w * 32 + ct * 16 + l15];
    f32x4 acc[4][2];
#pragma unroll
    for (int rt = 0; rt < 4; ++rt)
#pragma unroll
        for (int ct = 0; ct < 2; ++ct) { f32x4 a = {bias[ct], bias[ct], bias[ct], bias[ct]}; acc[rt][ct] = a; }

    const int srow = tid >> 3;   // 0..63
    const int sc4 = tid & 7;     // float4 index within 32-col chunk

#pragma unroll 1
    for (int kc = 0; kc < 16; ++kc) {
        if (kc) __syncthreads();
        const float4 xv = *reinterpret_cast<const float4*>(X + (rowbase + srow) * 512 + kc * 32 + sc4 * 4);
        float x4[4] = {xv.x, xv.y, xv.z, xv.w};
        ushort_t hs[4], ls[4];
#pragma unroll
        for (int q = 0; q < 4; ++q) { hs[q] = f2bf(x4[q]); ls[q] = f2bf(x4[q] - bf2f(hs[q])); }
        *reinterpret_cast<ushort4*>(&Xs[0][srow][sc4 * 4]) = make_ushort4(hs[0], hs[1], hs[2], hs[3]);
        *reinterpret_cast<ushort4*>(&Xs[1][srow][sc4 * 4]) = make_ushort4(ls[0], ls[1], ls[2], ls[3]);
        __syncthreads();

        bf16x8 Ah[4], Al[4];
#pragma unroll
        for (int rt = 0; rt < 4; ++rt) {
            Ah[rt] = *reinterpret_cast<const bf16x8*>(&Xs[0][rt * 16 + l15][l4 * 8]);
            Al[rt] = *reinterpret_cast<const bf16x8*>(&Xs[1][rt * 16 + l15][l4 * 8]);
        }
#pragma unroll
        for (int ct = 0; ct < 2; ++ct) {
            const int nt = w * 2 + ct;
            bf16x8 Bh = *reinterpret_cast<const bf16x8*>(wd1f + foff(nt, 16, kc, 0, lane));
            bf16x8 Bl = *reinterpret_cast<const bf16x8*>(wd1f + foff(nt, 16, kc, 1, lane));
#pragma unroll
            for (int rt = 0; rt < 4; ++rt) {
                acc[rt][ct] = mfma16(Ah[rt], Bh, acc[rt][ct]);
                acc[rt][ct] = mfma16(Ah[rt], Bl, acc[rt][ct]);
                acc[rt][ct] = mfma16(Al[rt], Bh, acc[rt][ct]);
            }
        }
    }

    // epilogue: BN + LeakyReLU + split-bf16 store into s-fragment layout
#pragma unroll
    for (int ct = 0; ct < 2; ++ct) {
        const int col = w * 32 + ct * 16 + l15;
        const float sc = gam[col] * rsqrtf(var[col] + 1e-3f);
        const float sh = bet[col] - mu[col] * sc;
        const int t = col >> 4, f = col & 15;
        const int jp = f & 7;
#pragma unroll
        for (int rt = 0; rt < 4; ++rt) {
            const long rtg = (long)blk * 4 + rt;
#pragma unroll
            for (int jd = 0; jd < 4; ++jd) {
                float v = acc[rt][ct][jd] * sc + sh;
                v = (v >= 0.f) ? v : 0.2f * v;
                const int rowin = l4 * 4 + jd;                 // row within 16-tile (C/D layout, m89)
                const int lanep = rowin + ((f >> 3) << 4);
                const long base = (((rtg * 16 + t) * 2 + 0) * 32 + lanep) * 8 + jp;
                const ushort_t hi = f2bf(v);
                sfrag[base] = hi;
                sfrag[base + 256] = f2bf(v - bf2f(hi));        // plane-1 offset = 32*8
            }
        }
    }
}

// ---------------- kernel 2: LSTM1 + LSTM2 (lockstep) + Dense2 + softmax ----------------
// LDS: A[plane][row 0..63][cols: 0..31 = h2, 32..159 = h1], stride 168 elems (336B, odd x16B)
//      C1[row][unit] fp32 LSTM1 cell state (stride 132: 2-way bank aliasing only; thread-exclusive slots)
__global__ __launch_bounds__(NTHR, 1) void lstm_kernel(
    const ushort_t* __restrict__ wh1f, const ushort_t* __restrict__ wx1f,
    const ushort_t* __restrict__ w2f, const ushort_t* __restrict__ wd2f,
    const ushort_t* __restrict__ sfrag, const float* __restrict__ b1,
    const float* __restrict__ b2, const float* __restrict__ bd2,
    float* __restrict__ out) {
    __shared__ __align__(16) ushort_t A[2][64][168];   // 43008 B
    __shared__ float C1[64][132];                      // 33792 B
    const int tid = threadIdx.x;
    const int lane = tid & 63, w = tid >> 6;
    const int l4 = lane >> 4, l15 = lane & 15;
    const int blk = blockIdx.x;

    {   // zero-init state (h1 = h2 = 0, c1 = 0)
        unsigned long long* p = (unsigned long long*)&A[0][0][0];
#pragma unroll 4
        for (int i = tid; i < 2 * 64 * 168 / 4; i += NTHR) p[i] = 0ull;
        float* q = &C1[0][0];
#pragma unroll 4
        for (int i = tid; i < 64 * 132; i += NTHR) q[i] = 0.f;
    }

    float c2[4];
#pragma unroll
    for (int q = 0; q < 4; ++q) c2[q] = 0.f;

    const int u1 = w * 16 + l15;          // LSTM1: wave w owns units [16w,16w+16)
    float b1g[4];
#pragma unroll
    for (int g = 0; g < 4; ++g) b1g[g] = b1[g * 128 + u1];
    const int rt2 = w & 3;                // LSTM2: wave -> (row-tile, unit-half)
    const int u2base = (w >> 2) * 16;
    float b2g[4];
#pragma unroll
    for (int g = 0; g < 4; ++g) b2g[g] = b2[g * 32 + u2base + l15];

    __syncthreads();

#pragma unroll 1
    for (int t = 0; t < 16; ++t) {
        // ---- LSTM1 z = [h1 | s_t] @ [Wh1; Wx1] + b1 ----
        f32x4 acc1[4][4];
#pragma unroll
        for (int rt = 0; rt < 4; ++rt)
#pragma unroll
            for (int g = 0; g < 4; ++g) { f32x4 a = {b1g[g], b1g[g], b1g[g], b1g[g]}; acc1[rt][g] = a; }

#pragma unroll
        for (int kc = 0; kc < 4; ++kc) {           // h1 part (A cols 32..159)
            bf16x8 Ah[4], Al[4];
#pragma unroll
            for (int rt = 0; rt < 4; ++rt) {
                Ah[rt] = *reinterpret_cast<const bf16x8*>(&A[0][rt * 16 + l15][32 + kc * 32 + l4 * 8]);
                Al[rt] = *reinterpret_cast<const bf16x8*>(&A[1][rt * 16 + l15][32 + kc * 32 + l4 * 8]);
            }
#pragma unroll
            for (int g = 0; g < 4; ++g) {
                const int nt = g * 8 + w;
                bf16x8 Bh = *reinterpret_cast<const bf16x8*>(wh1f + foff(nt, 4, kc, 0, lane));
                bf16x8 Bl = *reinterpret_cast<const bf16x8*>(wh1f + foff(nt, 4, kc, 1, lane));
#pragma unroll
                for (int rt = 0; rt < 4; ++rt) {
                    acc1[rt][g] = mfma16(Ah[rt], Bh, acc1[rt][g]);
                    acc1[rt][g] = mfma16(Ah[rt], Bl, acc1[rt][g]);
                    acc1[rt][g] = mfma16(Al[rt], Bh, acc1[rt][g]);
                }
            }
        }
        {   // s_t part (K=16 padded to 32; weight rows >=16 are zero)
            bf16x8 Sh[4], Sl[4];
#pragma unroll
            for (int rt = 0; rt < 4; ++rt) {
                bf16x8 z = {};
                Sh[rt] = z; Sl[rt] = z;
                if (lane < 32) {
                    const long rtg = (long)blk * 4 + rt;
                    const long so = (((rtg * 16 + t) * 2 + 0) * 32 + lane) * 8;
                    Sh[rt] = *reinterpret_cast<const bf16x8*>(sfrag + so);
                    Sl[rt] = *reinterpret_cast<const bf16x8*>(sfrag + so + 256);
                }
            }
#pragma unroll
            for (int g = 0; g < 4; ++g) {
                const int nt = g * 8 + w;
                bf16x8 Bh = *reinterpret_cast<const bf16x8*>(wx1f + foff(nt, 1, 0, 0, lane));
                bf16x8 Bl = *reinterpret_cast<const bf16x8*>(wx1f + foff(nt, 1, 0, 1, lane));
#pragma unroll
                for (int rt = 0; rt < 4; ++rt) {
                    acc1[rt][g] = mfma16(Sh[rt], Bh, acc1[rt][g]);
                    acc1[rt][g] = mfma16(Sh[rt], Bl, acc1[rt][g]);
                    acc1[rt][g] = mfma16(Sl[rt], Bh, acc1[rt][g]);
                }
            }
        }
        __syncthreads();   // B1: all z1 reads of h1_old complete
        // gates (Keras order i,f,g,o) AFTER B1: c from LDS, h written straight to LDS (no hn1/c1 regs)
#pragma unroll
        for (int rt = 0; rt < 4; ++rt) {
#pragma unroll
            for (int jd = 0; jd < 4; ++jd) {
                const int row = rt * 16 + l4 * 4 + jd;         // C/D layout (m89)
                const float ig = sigm(acc1[rt][0][jd]);
                const float fg = sigm(acc1[rt][1][jd]);
                const float gg = tanhc(acc1[rt][2][jd]);
                const float og = sigm(acc1[rt][3][jd]);
                const float c = fg * C1[row][u1] + ig * gg;
                C1[row][u1] = c;
                const float v = og * tanhc(c);
                const ushort_t hi = f2bf(v);
                A[0][row][32 + u1] = hi;
                A[1][row][32 + u1] = f2bf(v - bf2f(hi));
            }
        }
        __syncthreads();   // B2: h1_new visible
        // ---- LSTM2 z = [h2_old | h1_new] @ [Wh2; Wx2] + b2 ----
        f32x4 acc2[4];
#pragma unroll
        for (int g = 0; g < 4; ++g) { f32x4 a = {b2g[g], b2g[g], b2g[g], b2g[g]}; acc2[g] = a; }
#pragma unroll
        for (int kc = 0; kc < 5; ++kc) {
            bf16x8 Ah2 = *reinterpret_cast<const bf16x8*>(&A[0][rt2 * 16 + l15][kc * 32 + l4 * 8]);
            bf16x8 Al2 = *reinterpret_cast<const bf16x8*>(&A[1][rt2 * 16 + l15][kc * 32 + l4 * 8]);
#pragma unroll
            for (int g = 0; g < 4; ++g) {
                const int nt = g * 2 + (w >> 2);
                bf16x8 Bh = *reinterpret_cast<const bf16x8*>(w2f + foff(nt, 5, kc, 0, lane));
                bf16x8 Bl = *reinterpret_cast<const bf16x8*>(w2f + foff(nt, 5, kc, 1, lane));
                acc2[g] = mfma16(Ah2, Bh, acc2[g]);
                acc2[g] = mfma16(Ah2, Bl, acc2[g]);
                acc2[g] = mfma16(Al2, Bh, acc2[g]);
            }
        }
        float hn2[4];
#pragma unroll
        for (int jd = 0; jd < 4; ++jd) {
            const float ig = sigm(acc2[0][jd]);
            const float fg = sigm(acc2[1][jd]);
            const float gg = tanhc(acc2[2][jd]);
            const float og = sigm(acc2[3][jd]);
            const float c = fg * c2[jd] + ig * gg;
            c2[jd] = c;
            hn2[jd] = og * tanhc(c);
        }
        __syncthreads();   // B3: all z2 reads of h2_old complete
#pragma unroll
        for (int jd = 0; jd < 4; ++jd) {
            const int row = rt2 * 16 + l4 * 4 + jd;
            const float v = hn2[jd];
            const ushort_t hi = f2bf(v);
            A[0][row][u2base + l15] = hi;
            A[1][row][u2base + l15] = f2bf(v - bf2f(hi));
        }
        // next z1 reads only h1 cols (no race with h2 writes); next z2 is behind B1+B2
    }
    __syncthreads();       // final h2 visible

    // ---- Dense2 (K=32) + softmax over 10 classes ----
    if (w < 4) {
        const int rt = w;
        bf16x8 Ah2 = *reinterpret_cast<const bf16x8*>(&A[0][rt * 16 + l15][l4 * 8]);
        bf16x8 Al2 = *reinterpret_cast<const bf16x8*>(&A[1][rt * 16 + l15][l4 * 8]);
        bf16x8 Bh = *reinterpret_cast<const bf16x8*>(wd2f + foff(0, 1, 0, 0, lane));
        bf16x8 Bl = *reinterpret_cast<const bf16x8*>(wd2f + foff(0, 1, 0, 1, lane));
        const float bb = (l15 < 10) ? bd2[l15] : 0.f;
        f32x4 accd = {bb, bb, bb, bb};
        accd = mfma16(Ah2, Bh, accd);
        accd = mfma16(Ah2, Bl, accd);
        accd = mfma16(Al2, Bh, accd);
#pragma unroll
        for (int jd = 0; jd < 4; ++jd) {
            float v = (l15 < 10) ? accd[jd] : -1e30f;
            float m = v;
            m = fmaxf(m, __shfl_xor(m, 1));
            m = fmaxf(m, __shfl_xor(m, 2));
            m = fmaxf(m, __shfl_xor(m, 4));
            m = fmaxf(m, __shfl_xor(m, 8));
            float e = (l15 < 10) ? __expf(v - m) : 0.f;
            float s = e;
            s += __shfl_xor(s, 1);
            s += __shfl_xor(s, 2);
            s += __shfl_xor(s, 4);
            s += __shfl_xor(s, 8);
            if (l15 < 10) {
                const long r = (long)blk * 64 + rt * 16 + l4 * 4 + jd;
                out[r * 10 + l15] = e / s;
            }
        }
    }
}

extern "C" void kernel_launch(void* const* d_in, const int* in_sizes, int n_in,
                              void* d_out, int out_size, void* d_ws, size_t ws_size,
                              hipStream_t stream) {
    const float* x   = (const float*)d_in[0];
    const float* Wd1 = (const float*)d_in[1];
    const float* bd1 = (const float*)d_in[2];
    const float* gam = (const float*)d_in[3];
    const float* bet = (const float*)d_in[4];
    const float* mu  = (const float*)d_in[5];
    const float* var = (const float*)d_in[6];
    const float* Wx1 = (const float*)d_in[7];
    const float* Wh1 = (const float*)d_in[8];
    const float* b1  = (const float*)d_in[9];
    const float* Wx2 = (const float*)d_in[10];
    const float* Wh2 = (const float*)d_in[11];
    const float* b2  = (const float*)d_in[12];
    const float* Wd2 = (const float*)d_in[13];
    const float* bd2 = (const float*)d_in[14];
    float* out = (float*)d_out;

    char* ws = (char*)d_ws;
    ushort_t* wd1f  = (ushort_t*)(ws);             // 524288 B
    ushort_t* wh1f  = (ushort_t*)(ws + 524288);    // 262144 B
    ushort_t* wx1f  = (ushort_t*)(ws + 786432);    // 65536 B
    ushort_t* w2f   = (ushort_t*)(ws + 851968);    // 81920 B
    ushort_t* wd2f  = (ushort_t*)(ws + 933888);    // 2048 B
    ushort_t* sfrag = (ushort_t*)(ws + 935936);    // 33554432 B  (total ~34.5 MB)

    hipLaunchKernelGGL(prep_weights, dim3(512), dim3(512), 0, stream,
                       Wd1, Wx1, Wh1, Wx2, Wh2, Wd2, wd1f, wh1f, wx1f, w2f, wd2f);
    hipLaunchKernelGGL(dense1_kernel, dim3(512), dim3(512), 0, stream,
                       x, bd1, gam, bet, mu, var, wd1f, sfrag);
    hipLaunchKernelGGL(lstm_kernel, dim3(512), dim3(512), 0, stream,
                       wh1f, wx1f, w2f, wd2f, sfrag, b1, b2, bd2, out);
}

// Round 12
// 904.302 us; speedup vs baseline: 1.0957x; 1.0748x over previous
//
#include <hip/hip_runtime.h>
#include <hip/hip_bf16.h>
#include <stdint.h>

// Fused: Dense(512->256)+BN+LeakyReLU -> LSTM(16x16 -> 128, seq) -> LSTM(128 -> 32) -> Dense(32->10)+softmax
// Strategy: split-bf16 (hi+lo) MFMA everywhere (3x mfma_f32_16x16x32_bf16 per fp32 MAC, ~8e-6 rel err).
// r2/r6: WRITE=267MB => ~16 regs/lane spilled per timestep; spill stream thrashes L2 => FETCH=2.04GB.
// r10: r7 (hn1/c1 -> LDS) ran (LDS 76800 confirms) and did NOT reduce spills (255MB) => binding pressure
//   is the scheduler pipelining the WHOLE timestep: sfrag/weight loads hoisted while acc1[4][4] (64 VGPR)
//   is live => peak ~150 regs regardless of named locals.
// r11 change (resubmitted r12; r11 bench never acquired a GPU): LSTM1 z computed in TWO sequential rt-pair
//   passes of acc[2][4] (32 VGPR each). Gates run inside each pass (C1 slots thread-exclusive => legal
//   pre-B1); h packed to hi|lo<<16 (16 u32 carried). sched_barrier(0) at the pass boundary stops
//   cross-pass load hoisting. Peak live ~103 < 128 => no spill, 4 waves/SIMD kept. Weights read 2x/t but
//   L1/L2-hot once spill stream stops thrashing L2.

typedef short bf16x8 __attribute__((ext_vector_type(8)));   // 8 bf16 payloads in 4 VGPRs (guide §3)
typedef float f32x4 __attribute__((ext_vector_type(4)));
typedef unsigned short ushort_t;

#define NTHR 512

__device__ __forceinline__ ushort_t f2bf(float f) {   // fp32 -> bf16 RNE (bit trick)
    unsigned u = __float_as_uint(f);
    u = u + 0x7fffu + ((u >> 16) & 1u);
    return (ushort_t)(u >> 16);
}
__device__ __forceinline__ float bf2f(ushort_t h) {
    return __uint_as_float(((unsigned)h) << 16);
}
__device__ __forceinline__ ushort_t planev(float v, int plane) {
    ushort_t hi = f2bf(v);
    if (plane == 0) return hi;
    return f2bf(v - bf2f(hi));                        // lo residual
}
// fragment-linear weight layout: off = (((nt*KC + kc)*2 + plane)*64 + lane)*8 + j
__device__ __forceinline__ int foff(int nt, int KC, int kc, int plane, int lane) {
    return (((nt * KC + kc) * 2 + plane) * 64 + lane) * 8;
}
__device__ __forceinline__ f32x4 mfma16(bf16x8 a, bf16x8 b, f32x4 c) {
    return __builtin_amdgcn_mfma_f32_16x16x32_bf16(a, b, c, 0, 0, 0);
}
__device__ __forceinline__ float sigm(float x) { return 1.0f / (1.0f + __expf(-x)); }
__device__ __forceinline__ float tanhc(float x) {
    x = fminf(15.0f, fmaxf(-15.0f, x));
    float e = __expf(2.0f * x);
    return (e - 1.0f) / (e + 1.0f);
}

// ---------------- prep: weights -> split-bf16 MFMA fragment layout in ws ----------------
// B-frag semantics: lane l holds W[k][n], n = nt*16 + (l&15), k = kc*32 + (l>>4)*8 + j (j=0..7)
__global__ void prep_weights(const float* __restrict__ Wd1, const float* __restrict__ Wx1,
                             const float* __restrict__ Wh1, const float* __restrict__ Wx2,
                             const float* __restrict__ Wh2, const float* __restrict__ Wd2,
                             ushort_t* __restrict__ wd1f, ushort_t* __restrict__ wh1f,
                             ushort_t* __restrict__ wx1f, ushort_t* __restrict__ w2f,
                             ushort_t* __restrict__ wd2f) {
    const int i = blockIdx.x * blockDim.x + threadIdx.x;   // 0..262143
    const int j = i & 7;
    const int lane = (i >> 3) & 63;
    const int plane = (i >> 9) & 1;
    const int rest = i >> 10;
    const int krow = ((lane >> 4) << 3) + j;
    const int ncol = lane & 15;
    {   // Wd1: K=512 (KC=16), N=256 (NT=16), 262144 slots
        const int kc = rest & 15, nt = rest >> 4;
        const int k = kc * 32 + krow, n = nt * 16 + ncol;
        wd1f[i] = planev(Wd1[k * 256 + n], plane);
    }
    if (i < 131072) {   // Wh1: K=128 (KC=4), N=512 (NT=32)
        const int kc = rest & 3, nt = rest >> 2;
        const int k = kc * 32 + krow, n = nt * 16 + ncol;
        wh1f[i] = planev(Wh1[k * 512 + n], plane);
    }
    if (i < 32768) {    // Wx1: K=16 padded to 32 (KC=1), N=512 (NT=32)
        const int nt = rest;
        const int k = krow, n = nt * 16 + ncol;
        const float v = (k < 16) ? Wx1[k * 512 + n] : 0.f;
        wx1f[i] = planev(v, plane);
    }
    if (i < 40960) {    // W2 = [Wh2(32); Wx2(128)]: K=160 (KC=5), N=128 (NT=8)
        const int kc = rest % 5, nt = rest / 5;
        const int k = kc * 32 + krow, n = nt * 16 + ncol;
        const float v = (k < 32) ? Wh2[k * 128 + n] : Wx2[(k - 32) * 128 + n];
        w2f[i] = planev(v, plane);
    }
    if (i < 1024) {     // Wd2: K=32 (KC=1), N=10 padded to 16 (NT=1)
        const int k = krow, n = ncol;
        const float v = (n < 10) ? Wd2[k * 10 + n] : 0.f;
        wd2f[i] = planev(v, plane);
    }
}

// ---------------- kernel 1: Dense1 + BN + LeakyReLU -> s-fragments (A-operand layout) ----------------
// sfrag element for (row, col): t=col>>4, f=col&15, lane' = (row&15) + 16*(f>>3), j'=f&7, rtg=row>>4
// off = (((rtg*16 + t)*2 + plane)*32 + lane')*8 + j'
__global__ __launch_bounds__(NTHR, 2) void dense1_kernel(
    const float* __restrict__ X, const float* __restrict__ bd1,
    const float* __restrict__ gam, const float* __restrict__ bet,
    const float* __restrict__ mu, const float* __restrict__ var,
    const ushort_t* __restrict__ wd1f, ushort_t* __restrict__ sfrag) {
    __shared__ __align__(16) ushort_t Xs[2][64][40];   // hi/lo planes, 80B row stride (odd x16B)
    const int tid = threadIdx.x;
    const int lane = tid & 63, w = tid >> 6;
    const int l4 = lane >> 4, l15 = lane & 15;
    const int blk = blockIdx.x;
    const long rowbase = (long)blk * 64;

    float bias[2];
#pragma unroll
    for (int ct = 0; ct < 2; ++ct) bias[ct] = bd1[w * 32 + ct * 16 + l15];
    f32x4 acc[4][2];
#pragma unroll
    for (int rt = 0; rt < 4; ++rt)
#pragma unroll
        for (int ct = 0; ct < 2; ++ct) { f32x4 a = {bias[ct], bias[ct], bias[ct], bias[ct]}; acc[rt][ct] = a; }

    const int srow = tid >> 3;   // 0..63
    const int sc4 = tid & 7;     // float4 index within 32-col chunk

#pragma unroll 1
    for (int kc = 0; kc < 16; ++kc) {
        if (kc) __syncthreads();
        const float4 xv = *reinterpret_cast<const float4*>(X + (rowbase + srow) * 512 + kc * 32 + sc4 * 4);
        float x4[4] = {xv.x, xv.y, xv.z, xv.w};
        ushort_t hs[4], ls[4];
#pragma unroll
        for (int q = 0; q < 4; ++q) { hs[q] = f2bf(x4[q]); ls[q] = f2bf(x4[q] - bf2f(hs[q])); }
        *reinterpret_cast<ushort4*>(&Xs[0][srow][sc4 * 4]) = make_ushort4(hs[0], hs[1], hs[2], hs[3]);
        *reinterpret_cast<ushort4*>(&Xs[1][srow][sc4 * 4]) = make_ushort4(ls[0], ls[1], ls[2], ls[3]);
        __syncthreads();

        bf16x8 Ah[4], Al[4];
#pragma unroll
        for (int rt = 0; rt < 4; ++rt) {
            Ah[rt] = *reinterpret_cast<const bf16x8*>(&Xs[0][rt * 16 + l15][l4 * 8]);
            Al[rt] = *reinterpret_cast<const bf16x8*>(&Xs[1][rt * 16 + l15][l4 * 8]);
        }
#pragma unroll
        for (int ct = 0; ct < 2; ++ct) {
            const int nt = w * 2 + ct;
            bf16x8 Bh = *reinterpret_cast<const bf16x8*>(wd1f + foff(nt, 16, kc, 0, lane));
            bf16x8 Bl = *reinterpret_cast<const bf16x8*>(wd1f + foff(nt, 16, kc, 1, lane));
#pragma unroll
            for (int rt = 0; rt < 4; ++rt) {
                acc[rt][ct] = mfma16(Ah[rt], Bh, acc[rt][ct]);
                acc[rt][ct] = mfma16(Ah[rt], Bl, acc[rt][ct]);
                acc[rt][ct] = mfma16(Al[rt], Bh, acc[rt][ct]);
            }
        }
    }

    // epilogue: BN + LeakyReLU + split-bf16 store into s-fragment layout
#pragma unroll
    for (int ct = 0; ct < 2; ++ct) {
        const int col = w * 32 + ct * 16 + l15;
        const float sc = gam[col] * rsqrtf(var[col] + 1e-3f);
        const float sh = bet[col] - mu[col] * sc;
        const int t = col >> 4, f = col & 15;
        const int jp = f & 7;
#pragma unroll
        for (int rt = 0; rt < 4; ++rt) {
            const long rtg = (long)blk * 4 + rt;
#pragma unroll
            for (int jd = 0; jd < 4; ++jd) {
                float v = acc[rt][ct][jd] * sc + sh;
                v = (v >= 0.f) ? v : 0.2f * v;
                const int rowin = l4 * 4 + jd;                 // row within 16-tile (C/D layout, m89)
                const int lanep = rowin + ((f >> 3) << 4);
                const long base = (((rtg * 16 + t) * 2 + 0) * 32 + lanep) * 8 + jp;
                const ushort_t hi = f2bf(v);
                sfrag[base] = hi;
                sfrag[base + 256] = f2bf(v - bf2f(hi));        // plane-1 offset = 32*8
            }
        }
    }
}

// ---------------- kernel 2: LSTM1 (two rt-pair passes) + LSTM2 + Dense2 + softmax ----------------
// LDS: A[plane][row 0..63][cols: 0..31 = h2, 32..159 = h1], stride 168 elems (336B, odd x16B)
//      C1[row][unit] fp32 LSTM1 cell state (stride 132: 2-way bank aliasing only; thread-exclusive slots)
// One pass: z1 for rows [RT0*16, RT0*16+32) -> gates -> h packed into hpk (A-writes deferred past B1).
#define Z1_PASS(RT0)                                                                              \
    {                                                                                             \
        f32x4 acc[2][4];                                                                          \
        _Pragma("unroll")                                                                         \
        for (int r2 = 0; r2 < 2; ++r2)                                                            \
            _Pragma("unroll")                                                                     \
            for (int g = 0; g < 4; ++g) {                                                         \
                f32x4 a = {b1g[g], b1g[g], b1g[g], b1g[g]};                                       \
                acc[r2][g] = a;                                                                   \
            }                                                                                     \
        _Pragma("unroll")                                                                         \
        for (int kc = 0; kc < 4; ++kc) {                                                          \
            bf16x8 Ah[2], Al[2];                                                                  \
            _Pragma("unroll")                                                                     \
            for (int r2 = 0; r2 < 2; ++r2) {                                                      \
                Ah[r2] = *reinterpret_cast<const bf16x8*>(                                        \
                    &A[0][(RT0 + r2) * 16 + l15][32 + kc * 32 + l4 * 8]);                         \
                Al[r2] = *reinterpret_cast<const bf16x8*>(                                        \
                    &A[1][(RT0 + r2) * 16 + l15][32 + kc * 32 + l4 * 8]);                         \
            }                                                                                     \
            _Pragma("unroll")                                                                     \
            for (int g = 0; g < 4; ++g) {                                                         \
                const int nt = g * 8 + w;                                                         \
                bf16x8 Bh = *reinterpret_cast<const bf16x8*>(wh1f + foff(nt, 4, kc, 0, lane));    \
                bf16x8 Bl = *reinterpret_cast<const bf16x8*>(wh1f + foff(nt, 4, kc, 1, lane));    \
                _Pragma("unroll")                                                                 \
                for (int r2 = 0; r2 < 2; ++r2) {                                                  \
                    acc[r2][g] = mfma16(Ah[r2], Bh, acc[r2][g]);                                  \
                    acc[r2][g] = mfma16(Ah[r2], Bl, acc[r2][g]);                                  \
                    acc[r2][g] = mfma16(Al[r2], Bh, acc[r2][g]);                                  \
                }                                                                                 \
            }                                                                                     \
        }                                                                                         \
        {                                                                                         \
            bf16x8 Sh[2], Sl[2];                                                                  \
            _Pragma("unroll")                                                                     \
            for (int r2 = 0; r2 < 2; ++r2) {                                                      \
                bf16x8 z = {};                                                                    \
                Sh[r2] = z; Sl[r2] = z;                                                           \
                if (lane < 32) {                                                                  \
                    const long rtg = (long)blk * 4 + (RT0 + r2);                                  \
                    const long so = (((rtg * 16 + t) * 2 + 0) * 32 + lane) * 8;                   \
                    Sh[r2] = *reinterpret_cast<const bf16x8*>(sfrag + so);                        \
                    Sl[r2] = *reinterpret_cast<const bf16x8*>(sfrag + so + 256);                  \
                }                                                                                 \
            }                                                                                     \
            _Pragma("unroll")                                                                     \
            for (int g = 0; g < 4; ++g) {                                                         \
                const int nt = g * 8 + w;                                                         \
                bf16x8 Bh = *reinterpret_cast<const bf16x8*>(wx1f + foff(nt, 1, 0, 0, lane));     \
                bf16x8 Bl = *reinterpret_cast<const bf16x8*>(wx1f + foff(nt, 1, 0, 1, lane));     \
                _Pragma("unroll")                                                                 \
                for (int r2 = 0; r2 < 2; ++r2) {                                                  \
                    acc[r2][g] = mfma16(Sh[r2], Bh, acc[r2][g]);                                  \
                    acc[r2][g] = mfma16(Sh[r2], Bl, acc[r2][g]);                                  \
                    acc[r2][g] = mfma16(Sl[r2], Bh, acc[r2][g]);                                  \
                }                                                                                 \
            }                                                                                     \
        }                                                                                         \
        _Pragma("unroll")                                                                         \
        for (int r2 = 0; r2 < 2; ++r2) {                                                          \
            _Pragma("unroll")                                                                     \
            for (int jd = 0; jd < 4; ++jd) {                                                      \
                const int row = (RT0 + r2) * 16 + l4 * 4 + jd;   /* C/D layout (m89) */           \
                const float ig = sigm(acc[r2][0][jd]);                                            \
                const float fg = sigm(acc[r2][1][jd]);                                            \
                const float gg = tanhc(acc[r2][2][jd]);                                           \
                const float og = sigm(acc[r2][3][jd]);                                            \
                const float c = fg * C1[row][u1] + ig * gg;                                       \
                C1[row][u1] = c;                                                                  \
                const float v = og * tanhc(c);                                                    \
                const ushort_t hi = f2bf(v);                                                      \
                const ushort_t lo = f2bf(v - bf2f(hi));                                           \
                hpk[RT0 + r2][jd] = (unsigned)hi | ((unsigned)lo << 16);                          \
            }                                                                                     \
        }                                                                                         \
    }

__global__ __launch_bounds__(NTHR, 1) void lstm_kernel(
    const ushort_t* __restrict__ wh1f, const ushort_t* __restrict__ wx1f,
    const ushort_t* __restrict__ w2f, const ushort_t* __restrict__ wd2f,
    const ushort_t* __restrict__ sfrag, const float* __restrict__ b1,
    const float* __restrict__ b2, const float* __restrict__ bd2,
    float* __restrict__ out) {
    __shared__ __align__(16) ushort_t A[2][64][168];   // 43008 B
    __shared__ float C1[64][132];                      // 33792 B
    const int tid = threadIdx.x;
    const int lane = tid & 63, w = tid >> 6;
    const int l4 = lane >> 4, l15 = lane & 15;
    const int blk = blockIdx.x;

    {   // zero-init state (h1 = h2 = 0, c1 = 0)
        unsigned long long* p = (unsigned long long*)&A[0][0][0];
#pragma unroll 4
        for (int i = tid; i < 2 * 64 * 168 / 4; i += NTHR) p[i] = 0ull;
        float* q = &C1[0][0];
#pragma unroll 4
        for (int i = tid; i < 64 * 132; i += NTHR) q[i] = 0.f;
    }

    float c2[4];
#pragma unroll
    for (int q = 0; q < 4; ++q) c2[q] = 0.f;

    const int u1 = w * 16 + l15;          // LSTM1: wave w owns units [16w,16w+16)
    float b1g[4];
#pragma unroll
    for (int g = 0; g < 4; ++g) b1g[g] = b1[g * 128 + u1];
    const int rt2 = w & 3;                // LSTM2: wave -> (row-tile, unit-half)
    const int u2base = (w >> 2) * 16;
    float b2g[4];
#pragma unroll
    for (int g = 0; g < 4; ++g) b2g[g] = b2[g * 32 + u2base + l15];

    __syncthreads();

#pragma unroll 1
    for (int t = 0; t < 16; ++t) {
        unsigned hpk[4][4];                // packed h1_new (hi | lo<<16), static-indexed only
        Z1_PASS(0)
        __builtin_amdgcn_sched_barrier(0);  // stop cross-pass load hoisting (live-range control)
        Z1_PASS(2)
        __syncthreads();   // B1: all z1 reads of h1_old complete
#pragma unroll
        for (int rt = 0; rt < 4; ++rt) {
#pragma unroll
            for (int jd = 0; jd < 4; ++jd) {
                const int row = rt * 16 + l4 * 4 + jd;
                const unsigned p = hpk[rt][jd];
                A[0][row][32 + u1] = (ushort_t)(p & 0xffffu);
                A[1][row][32 + u1] = (ushort_t)(p >> 16);
            }
        }
        __syncthreads();   // B2: h1_new visible
        // ---- LSTM2 z = [h2_old | h1_new] @ [Wh2; Wx2] + b2 ----
        f32x4 acc2[4];
#pragma unroll
        for (int g = 0; g < 4; ++g) { f32x4 a = {b2g[g], b2g[g], b2g[g], b2g[g]}; acc2[g] = a; }
#pragma unroll
        for (int kc = 0; kc < 5; ++kc) {
            bf16x8 Ah2 = *reinterpret_cast<const bf16x8*>(&A[0][rt2 * 16 + l15][kc * 32 + l4 * 8]);
            bf16x8 Al2 = *reinterpret_cast<const bf16x8*>(&A[1][rt2 * 16 + l15][kc * 32 + l4 * 8]);
#pragma unroll
            for (int g = 0; g < 4; ++g) {
                const int nt = g * 2 + (w >> 2);
                bf16x8 Bh = *reinterpret_cast<const bf16x8*>(w2f + foff(nt, 5, kc, 0, lane));
                bf16x8 Bl = *reinterpret_cast<const bf16x8*>(w2f + foff(nt, 5, kc, 1, lane));
                acc2[g] = mfma16(Ah2, Bh, acc2[g]);
                acc2[g] = mfma16(Ah2, Bl, acc2[g]);
                acc2[g] = mfma16(Al2, Bh, acc2[g]);
            }
        }
        float hn2[4];
#pragma unroll
        for (int jd = 0; jd < 4; ++jd) {
            const float ig = sigm(acc2[0][jd]);
            const float fg = sigm(acc2[1][jd]);
            const float gg = tanhc(acc2[2][jd]);
            const float og = sigm(acc2[3][jd]);
            const float c = fg * c2[jd] + ig * gg;
            c2[jd] = c;
            hn2[jd] = og * tanhc(c);
        }
        __syncthreads();   // B3: all z2 reads of h2_old complete
#pragma unroll
        for (int jd = 0; jd < 4; ++jd) {
            const int row = rt2 * 16 + l4 * 4 + jd;
            const float v = hn2[jd];
            const ushort_t hi = f2bf(v);
            A[0][row][u2base + l15] = hi;
            A[1][row][u2base + l15] = f2bf(v - bf2f(hi));
        }
        // next z1 reads only h1 cols (no race with h2 writes); next z2 is behind B1+B2
    }
    __syncthreads();       // final h2 visible

    // ---- Dense2 (K=32) + softmax over 10 classes ----
    if (w < 4) {
        const int rt = w;
        bf16x8 Ah2 = *reinterpret_cast<const bf16x8*>(&A[0][rt * 16 + l15][l4 * 8]);
        bf16x8 Al2 = *reinterpret_cast<const bf16x8*>(&A[1][rt * 16 + l15][l4 * 8]);
        bf16x8 Bh = *reinterpret_cast<const bf16x8*>(wd2f + foff(0, 1, 0, 0, lane));
        bf16x8 Bl = *reinterpret_cast<const bf16x8*>(wd2f + foff(0, 1, 0, 1, lane));
        const float bb = (l15 < 10) ? bd2[l15] : 0.f;
        f32x4 accd = {bb, bb, bb, bb};
        accd = mfma16(Ah2, Bh, accd);
        accd = mfma16(Ah2, Bl, accd);
        accd = mfma16(Al2, Bh, accd);
#pragma unroll
        for (int jd = 0; jd < 4; ++jd) {
            float v = (l15 < 10) ? accd[jd] : -1e30f;
            float m = v;
            m = fmaxf(m, __shfl_xor(m, 1));
            m = fmaxf(m, __shfl_xor(m, 2));
            m = fmaxf(m, __shfl_xor(m, 4));
            m = fmaxf(m, __shfl_xor(m, 8));
            float e = (l15 < 10) ? __expf(v - m) : 0.f;
            float s = e;
            s += __shfl_xor(s, 1);
            s += __shfl_xor(s, 2);
            s += __shfl_xor(s, 4);
            s += __shfl_xor(s, 8);
            if (l15 < 10) {
                const long r = (long)blk * 64 + rt * 16 + l4 * 4 + jd;
                out[r * 10 + l15] = e / s;
            }
        }
    }
}

extern "C" void kernel_launch(void* const* d_in, const int* in_sizes, int n_in,
                              void* d_out, int out_size, void* d_ws, size_t ws_size,
                              hipStream_t stream) {
    const float* x   = (const float*)d_in[0];
    const float* Wd1 = (const float*)d_in[1];
    const float* bd1 = (const float*)d_in[2];
    const float* gam = (const float*)d_in[3];
    const float* bet = (const float*)d_in[4];
    const float* mu  = (const float*)d_in[5];
    const float* var = (const float*)d_in[6];
    const float* Wx1 = (const float*)d_in[7];
    const float* Wh1 = (const float*)d_in[8];
    const float* b1  = (const float*)d_in[9];
    const float* Wx2 = (const float*)d_in[10];
    const float* Wh2 = (const float*)d_in[11];
    const float* b2  = (const float*)d_in[12];
    const float* Wd2 = (const float*)d_in[13];
    const float* bd2 = (const float*)d_in[14];
    float* out = (float*)d_out;

    char* ws = (char*)d_ws;
    ushort_t* wd1f  = (ushort_t*)(ws);             // 524288 B
    ushort_t* wh1f  = (ushort_t*)(ws + 524288);    // 262144 B
    ushort_t* wx1f  = (ushort_t*)(ws + 786432);    // 65536 B
    ushort_t* w2f   = (ushort_t*)(ws + 851968);    // 81920 B
    ushort_t* wd2f  = (ushort_t*)(ws + 933888);    // 2048 B
    ushort_t* sfrag = (ushort_t*)(ws + 935936);    // 33554432 B  (total ~34.5 MB)

    hipLaunchKernelGGL(prep_weights, dim3(512), dim3(512), 0, stream,
                       Wd1, Wx1, Wh1, Wx2, Wh2, Wd2, wd1f, wh1f, wx1f, w2f, wd2f);
    hipLaunchKernelGGL(dense1_kernel, dim3(512), dim3(512), 0, stream,
                       x, bd1, gam, bet, mu, var, wd1f, sfrag);
    hipLaunchKernelGGL(lstm_kernel, dim3(512), dim3(512), 0, stream,
                       wh1f, wx1f, w2f, wd2f, sfrag, b1, b2, bd2, out);
}